// Round 6
// baseline (17408.421 us; speedup 1.0000x reference)
//
#include <hip/hip_runtime.h>
#include <cstdint>
#include <cstddef>

#define B_  32
#define T_  2048
#define D_  512
#define H_  512
#define NWG 32   // recurrent workgroups; each owns 16 h-cols = 64 gate-cols

typedef unsigned int   u32;
typedef unsigned short u16;
typedef u32   u32x4  __attribute__((ext_vector_type(4)));
typedef u32   u32x2  __attribute__((ext_vector_type(2)));
typedef float f32x4  __attribute__((ext_vector_type(4)));
typedef __bf16 bf16x8 __attribute__((ext_vector_type(8)));

__device__ __forceinline__ u16 f2bf(float f) {
  u32 u = __builtin_bit_cast(u32, f);
  u32 r = (u + 0x7fffu + ((u >> 16) & 1u)) >> 16;   // RNE
  return (u16)r;
}
__device__ __forceinline__ f32x4 g4_from_bf(u32x2 p) {
  f32x4 r;
  r[0] = __builtin_bit_cast(float, (p[0] & 0xffffu) << 16);
  r[1] = __builtin_bit_cast(float, (p[0] & 0xffff0000u));
  r[2] = __builtin_bit_cast(float, (p[1] & 0xffffu) << 16);
  r[3] = __builtin_bit_cast(float, (p[1] & 0xffff0000u));
  return r;
}
__device__ __forceinline__ float sigm(float x) {
  return __builtin_amdgcn_rcpf(1.0f + __expf(-x));
}
__device__ __forceinline__ float tanh_fast(float x) {
  return 1.0f - 2.0f * __builtin_amdgcn_rcpf(__expf(2.0f * x) + 1.0f);
}

// ---------------------------------------------------------------------------
// K1: cast x [B][T][D] fp32 -> xb bf16, time-major rows m = t*32 + b
// ---------------------------------------------------------------------------
__global__ __launch_bounds__(256) void k_cast_x(const float* __restrict__ x,
                                                u16* __restrict__ xb) {
  long i = (long)blockIdx.x * 256 + threadIdx.x;
  int  dc = (int)(i & 63);
  long m  = i >> 6;
  int  t  = (int)(m >> 5), b = (int)(m & 31);
  const float* src = x + ((long)b * T_ + t) * D_ + (dc << 3);
  f32x4 a = *(const f32x4*)(src);
  f32x4 c = *(const f32x4*)(src + 4);
  u32x4 pv;
  pv[0] = (u32)f2bf(a[0]) | ((u32)f2bf(a[1]) << 16);
  pv[1] = (u32)f2bf(a[2]) | ((u32)f2bf(a[3]) << 16);
  pv[2] = (u32)f2bf(c[0]) | ((u32)f2bf(c[1]) << 16);
  pv[3] = (u32)f2bf(c[2]) | ((u32)f2bf(c[3]) << 16);
  *(u32x4*)(xb + (m << 9) + (dc << 3)) = pv;
}

// ---------------------------------------------------------------------------
// K2: pack weights transposed + gate-interleaved. col n = hcol*4 + gate.
// ---------------------------------------------------------------------------
__global__ __launch_bounds__(256) void k_pack_w(
    const float* __restrict__ Wxi, const float* __restrict__ Whi, const float* __restrict__ bi,
    const float* __restrict__ Wxf, const float* __restrict__ Whf, const float* __restrict__ bfv,
    const float* __restrict__ Wxo, const float* __restrict__ Who, const float* __restrict__ bo,
    const float* __restrict__ Wxc, const float* __restrict__ Whc, const float* __restrict__ bc,
    u16* __restrict__ w4xt, u16* __restrict__ w4ht, float* __restrict__ bias4) {
  int blk = blockIdx.x, tid = threadIdx.x;
  if (blk == 1024) {
    for (int i = tid; i < 2048; i += 256) {
      int hcol = i >> 2, g = i & 3;
      const float* bsrc = (g == 0 ? bi : g == 1 ? bfv : g == 2 ? bo : bc);
      bias4[i] = bsrc[hcol];
    }
    return;
  }
  bool isx = (blk < 512);
  long s = (long)(isx ? blk : blk - 512) * 256 + tid;
  int n = (int)(s >> 6);
  int c = (int)(s & 63);
  int hcol = n >> 2, g = n & 3;
  const float* W = isx ? (g == 0 ? Wxi : g == 1 ? Wxf : g == 2 ? Wxo : Wxc)
                       : (g == 0 ? Whi : g == 1 ? Whf : g == 2 ? Who : Whc);
  u16* dst = (isx ? w4xt : w4ht) + ((long)n << 9) + (c << 3);
#pragma unroll
  for (int j = 0; j < 8; j++) dst[j] = f2bf(W[(long)((c << 3) + j) * H_ + hcol]);
}

// ---------------------------------------------------------------------------
// K3: GEMM gates0[m][n] = sum_k xb[m][k]*w4xt[n][k] + bias4[n]
// ---------------------------------------------------------------------------
template <int G32>
__global__ __launch_bounds__(256) void k_gemm(const u16* __restrict__ xb,
                                              const u16* __restrict__ w4xt,
                                              const float* __restrict__ bias4,
                                              char* __restrict__ gates0) {
  __shared__ __align__(16) unsigned char As[128 * 32 * 2];
  __shared__ __align__(16) unsigned char Bs[128 * 32 * 2];
  int tid = threadIdx.x;
  int bm = blockIdx.x & 511;
  int bn = blockIdx.x >> 9;
  long m0 = (long)bm << 7;
  int  n0 = bn << 7;
  int wv = tid >> 6, lane = tid & 63;
  int wr = wv >> 1, wc = wv & 1;
  int lr = lane & 15, lc = lane >> 4;

  f32x4 acc[4][4];
#pragma unroll
  for (int i = 0; i < 4; i++)
#pragma unroll
    for (int j = 0; j < 4; j++) acc[i][j] = (f32x4){0.f, 0.f, 0.f, 0.f};

  for (int kt = 0; kt < 16; kt++) {
#pragma unroll
    for (int h = 0; h < 2; h++) {
      int s = h * 256 + tid;
      int row = s >> 2, ch = s & 3;
      u32x4 va = *(const u32x4*)(xb + ((m0 + row) << 9) + (kt << 5) + (ch << 3));
      *(u32x4*)(As + (((row << 6) + (ch << 4)) ^ ((row & 3) << 4))) = va;
      u32x4 vb = *(const u32x4*)(w4xt + (((long)n0 + row) << 9) + (kt << 5) + (ch << 3));
      *(u32x4*)(Bs + (((row << 6) + (ch << 4)) ^ ((row & 3) << 4))) = vb;
    }
    __syncthreads();
    bf16x8 af[4], bfr[4];
#pragma unroll
    for (int mi = 0; mi < 4; mi++) {
      int row = (wr << 6) + (mi << 4) + lr;
      af[mi] = __builtin_bit_cast(bf16x8,
          *(const u32x4*)(As + (((row << 6) + (lc << 4)) ^ ((row & 3) << 4))));
    }
#pragma unroll
    for (int ni = 0; ni < 4; ni++) {
      int row = (wc << 6) + (ni << 4) + lr;
      bfr[ni] = __builtin_bit_cast(bf16x8,
          *(const u32x4*)(Bs + (((row << 6) + (lc << 4)) ^ ((row & 3) << 4))));
    }
#pragma unroll
    for (int mi = 0; mi < 4; mi++)
#pragma unroll
      for (int ni = 0; ni < 4; ni++)
        acc[mi][ni] = __builtin_amdgcn_mfma_f32_16x16x32_bf16(af[mi], bfr[ni], acc[mi][ni], 0, 0, 0);
    __syncthreads();
  }
#pragma unroll
  for (int mi = 0; mi < 4; mi++) {
#pragma unroll
    for (int ni = 0; ni < 4; ni++) {
      int col = n0 + (wc << 6) + (ni << 4) + lr;
      float bias = bias4[col];
#pragma unroll
      for (int r = 0; r < 4; r++) {
        long row = m0 + (wr << 6) + (mi << 4) + (lc << 2) + r;
        float v = acc[mi][ni][r] + bias;
        if constexpr (G32) ((float*)gates0)[(row << 11) + col] = v;
        else               ((u16*)gates0)[(row << 11) + col] = f2bf(v);
      }
    }
  }
}

// ---------------------------------------------------------------------------
// K4: persistent recurrent kernel. grid=32, device-scope (sc1) flags + h.
//  - PER-WAVE flags (128): each wave drains its own 2 h-stores then publishes;
//    no __syncthreads anywhere in the loop -> waves fully decoupled.
//  - operand-swapped MFMA (A=Wh rows=gatecols, B=h cols=batch): all 4 gates
//    of cell (batch=lr, hcol=w*16+wv*4+lc) land in one lane's f32x4.
//  - split h-load wait vmcnt(16)/vmcnt(0); gates prefetch issued AFTER the
//    h-stores so the final counted vmcnt(2) drains stores but not gates.
// ---------------------------------------------------------------------------
template <int G32>
__global__ __launch_bounds__(256, 1) void k_rnn(const u16* __restrict__ w4ht,
                                                const char* __restrict__ gates0,
                                                const float* __restrict__ wd,
                                                u16* __restrict__ h_buf,   // [2][32][512]
                                                float* __restrict__ po,    // [T][128][32]
                                                u32* __restrict__ flags) { // [128] packed
  __shared__ __align__(16) unsigned char whs[64 * 1024];  // Wh slice, 64 KB

  const int tid = threadIdx.x;
  const int w = blockIdx.x;
  const int wv = tid >> 6, lane = tid & 63;
  const int lr = lane & 15, lc = lane >> 4;

  // stage Wh slice -> LDS (XOR-swizzled rows)
#pragma unroll 4
  for (int i = 0; i < 16; i++) {
    int s = i * 256 + tid;
    int n = s >> 6, c = s & 63;
    u32x4 v = *(const u32x4*)(w4ht + ((long)((w << 6) + n) << 9) + (c << 3));
    *(u32x4*)(whs + (((n << 10) + (c << 4)) ^ ((n & 7) << 4))) = v;
  }
  __syncthreads();

  const int mycol = (w << 4) + (wv << 2) + lc;        // this lane's h column
  const float wdr = wd[mycol];
  float c0 = 0.f, c1 = 0.f;

  const u32 hoff = (u32)((lr << 10) + (lc << 4));     // batch row lr, 16B chunk
  const u32 st0 = (u32)(((lr << 9) + mycol) << 1);
  const u32 st1 = (u32)((((lr + 16) << 9) + mycol) << 1);
  const u32 poll_off = (u32)(lane << 3);              // flags[2*lane..2*lane+1]
  const u32 flag_off = (u32)(((w << 2) + wv) << 2);   // flags[w*4+wv]

  const int sh = G32 ? 2 : 1;
  u32 go = (u32)(((lr << 11) + (mycol << 2)) << sh);  // gates0 byte offset @t=0
  const u32 gstep = 65536u << sh;                     // +1 timestep
  const u32 gdel  = 32768u << sh;                     // +16 batch rows

  // prologue: issue gates[0]
  u32x4 gfa, gfb, gna, gnb;
  u32x2 g2a, g2b, g2na, g2nb;
  if constexpr (G32) {
    asm volatile("global_load_dwordx4 %0, %1, %2" : "=v"(gfa) : "v"(go), "s"(gates0));
    asm volatile("global_load_dwordx4 %0, %1, %2" : "=v"(gfb) : "v"(go + gdel), "s"(gates0));
  } else {
    asm volatile("global_load_dwordx2 %0, %1, %2" : "=v"(g2a) : "v"(go), "s"(gates0));
    asm volatile("global_load_dwordx2 %0, %1, %2" : "=v"(g2b) : "v"(go + gdel), "s"(gates0));
  }

  const u32 wrow  = (u32)((wv << 4) + lr);            // LDS Wh row (gate-col)
  const u32 wbase = wrow << 10;
  const u32 wswz  = (wrow & 7) << 4;

#pragma unroll 1
  for (int t = 0; t < T_; t++) {
    const u16* hb_cur = h_buf + ((t & 1) << 14);
    u16* hb_nxt = h_buf + (((t + 1) & 1) << 14);

    // ---- poll: every wave needs all 128 per-wave flags >= t
    if (t > 0) {
      u32x2 fv;
      do {
        asm volatile("global_load_dwordx2 %0, %1, %2 sc1\n\ts_waitcnt vmcnt(0)"
                     : "=v"(fv) : "v"(poll_off), "s"(flags) : "memory");
      } while (!__all((fv[0] >= (u32)t) && (fv[1] >= (u32)t)));
    }

    // ---- h loads: 32 x 16B, device scope (pairs kk=0..15, issue order = kk)
    u32x4 hlo[16], hhi[16];
#pragma unroll
    for (int kk = 0; kk < 16; kk++) {
      asm volatile("global_load_dwordx4 %0, %1, %2 sc1"
                   : "=v"(hlo[kk]) : "v"(hoff + (u32)(kk << 6)), "s"(hb_cur));
      asm volatile("global_load_dwordx4 %0, %1, %2 sc1"
                   : "=v"(hhi[kk]) : "v"(hoff + (u32)(kk << 6) + 16384u), "s"(hb_cur));
    }

    // ---- G = Wh_slice @ h; D: col=lr=batch, row=lc*4+r=gatecol-within-wave
    f32x4 aL0 = {0.f,0.f,0.f,0.f}, aL1 = {0.f,0.f,0.f,0.f};
    f32x4 aH0 = {0.f,0.f,0.f,0.f}, aH1 = {0.f,0.f,0.f,0.f};
    asm volatile("s_waitcnt vmcnt(16)" ::: "memory");  // pairs 0..7 resident
    __builtin_amdgcn_sched_barrier(0);
#pragma unroll
    for (int kk = 0; kk < 8; kk++) {
      bf16x8 aw = __builtin_bit_cast(bf16x8,
          *(const u32x4*)(whs + ((wbase + (u32)((kk << 6) + (lc << 4))) ^ wswz)));
      bf16x8 bl = __builtin_bit_cast(bf16x8, hlo[kk]);
      bf16x8 bh = __builtin_bit_cast(bf16x8, hhi[kk]);
      if (kk & 1) {
        aL1 = __builtin_amdgcn_mfma_f32_16x16x32_bf16(aw, bl, aL1, 0, 0, 0);
        aH1 = __builtin_amdgcn_mfma_f32_16x16x32_bf16(aw, bh, aH1, 0, 0, 0);
      } else {
        aL0 = __builtin_amdgcn_mfma_f32_16x16x32_bf16(aw, bl, aL0, 0, 0, 0);
        aH0 = __builtin_amdgcn_mfma_f32_16x16x32_bf16(aw, bh, aH0, 0, 0, 0);
      }
    }
    asm volatile("s_waitcnt vmcnt(0)" ::: "memory");   // all h resident
    __builtin_amdgcn_sched_barrier(0);
#pragma unroll
    for (int kk = 8; kk < 16; kk++) {
      bf16x8 aw = __builtin_bit_cast(bf16x8,
          *(const u32x4*)(whs + ((wbase + (u32)((kk << 6) + (lc << 4))) ^ wswz)));
      bf16x8 bl = __builtin_bit_cast(bf16x8, hlo[kk]);
      bf16x8 bh = __builtin_bit_cast(bf16x8, hhi[kk]);
      if (kk & 1) {
        aL1 = __builtin_amdgcn_mfma_f32_16x16x32_bf16(aw, bl, aL1, 0, 0, 0);
        aH1 = __builtin_amdgcn_mfma_f32_16x16x32_bf16(aw, bh, aH1, 0, 0, 0);
      } else {
        aL0 = __builtin_amdgcn_mfma_f32_16x16x32_bf16(aw, bl, aL0, 0, 0, 0);
        aH0 = __builtin_amdgcn_mfma_f32_16x16x32_bf16(aw, bh, aH0, 0, 0, 0);
      }
    }
    f32x4 GL = aL0 + aL1, GH = aH0 + aH1;

    // ---- LSTM cell (fully in-lane): GL/GH[r] = gate r (i,f,o,c)
    f32x4 g0a, g0b;
    if constexpr (G32) {
      g0a = __builtin_bit_cast(f32x4, gfa);
      g0b = __builtin_bit_cast(f32x4, gfb);
    } else {
      g0a = g4_from_bf(g2a);
      g0b = g4_from_bf(g2b);
    }

    float I  = sigm(GL[0] + g0a[0]);
    float F  = sigm(GL[1] + g0a[1]);
    float O  = sigm(GL[2] + g0a[2]);
    float Ct = tanh_fast(GL[3] + g0a[3]);
    float cn = F * c0 + I * Ct;
    float hn = O * tanh_fast(cn);
    c0 = cn;
    u32 hv0 = (u32)f2bf(hn);
    asm volatile("global_store_short %0, %1, %2 sc1"
                 :: "v"(st0), "v"(hv0), "s"(hb_nxt) : "memory");

    float I2  = sigm(GH[0] + g0b[0]);
    float F2  = sigm(GH[1] + g0b[1]);
    float O2  = sigm(GH[2] + g0b[2]);
    float Ct2 = tanh_fast(GH[3] + g0b[3]);
    float cn2 = F2 * c1 + I2 * Ct2;
    float hn2 = O2 * tanh_fast(cn2);
    c1 = cn2;
    u32 hv1 = (u32)f2bf(hn2);
    asm volatile("global_store_short %0, %1, %2 sc1"
                 :: "v"(st1), "v"(hv1), "s"(hb_nxt) : "memory");

    // ---- gates prefetch t+1 (issued after stores: newest 2 vmem ops)
    u32 gq = (t + 1 < T_) ? (go + gstep) : go;
    if constexpr (G32) {
      asm volatile("global_load_dwordx4 %0, %1, %2" : "=v"(gna) : "v"(gq), "s"(gates0));
      asm volatile("global_load_dwordx4 %0, %1, %2" : "=v"(gnb) : "v"(gq + gdel), "s"(gates0));
    } else {
      asm volatile("global_load_dwordx2 %0, %1, %2" : "=v"(g2na) : "v"(gq), "s"(gates0));
      asm volatile("global_load_dwordx2 %0, %1, %2" : "=v"(g2nb) : "v"(gq + gdel), "s"(gates0));
    }
    go = gq;

    // drain the 2 h-stores (older than the 2 gate loads) -> publish flag
    asm volatile("s_waitcnt vmcnt(2)" ::: "memory");
    __builtin_amdgcn_sched_barrier(0);
    if (lane == 0) {
      u32 fval = (u32)(t + 1);
      asm volatile("global_store_dword %0, %1, %2 sc1"
                   :: "v"(flag_off), "v"(fval), "s"(flags) : "memory");
    }

    // ---- Wd partial (off critical path): reduce over lc within wave
    float p0 = hn * wdr, p1 = hn2 * wdr;
    p0 += __shfl_xor(p0, 16); p0 += __shfl_xor(p0, 32);
    p1 += __shfl_xor(p1, 16); p1 += __shfl_xor(p1, 32);
    if (lc == 0) {
      float* pp = po + ((long)t * 128 + (w << 2) + wv) * 32;
      pp[lr] = p0;
      pp[lr + 16] = p1;
    }

    // rotate prefetched gates
    if constexpr (G32) { gfa = gna; gfb = gnb; }
    else               { g2a = g2na; g2b = g2nb; }
  }
}

// ---------------------------------------------------------------------------
// K5: out[b,t] = sum_{128 wave partials} po[t][s][b] + bd
// ---------------------------------------------------------------------------
__global__ __launch_bounds__(256) void k_reduce(const float* __restrict__ po,
                                                const float* __restrict__ bd,
                                                float* __restrict__ out) {
  int tid = threadIdx.x;
  int b = tid & 31, tl = tid >> 5;
  int t = blockIdx.x * 8 + tl;
  float s = bd[0];
#pragma unroll 8
  for (int w = 0; w < 128; w++) s += po[((long)t * 128 + w) * 32 + b];
  out[(long)b * T_ + t] = s;
}

// ---------------------------------------------------------------------------
extern "C" void kernel_launch(void* const* d_in, const int* in_sizes, int n_in,
                              void* d_out, int out_size, void* d_ws, size_t ws_size,
                              hipStream_t stream) {
  const float* x   = (const float*)d_in[0];
  const float* Wxi = (const float*)d_in[1];
  const float* Whi = (const float*)d_in[2];
  const float* bi  = (const float*)d_in[3];
  const float* Wxf = (const float*)d_in[4];
  const float* Whf = (const float*)d_in[5];
  const float* bfv = (const float*)d_in[6];
  const float* Wxo = (const float*)d_in[7];
  const float* Who = (const float*)d_in[8];
  const float* bo  = (const float*)d_in[9];
  const float* Wxc = (const float*)d_in[10];
  const float* Whc = (const float*)d_in[11];
  const float* bc  = (const float*)d_in[12];
  const float* Wd  = (const float*)d_in[13];
  const float* bd  = (const float*)d_in[14];

  char* ws = (char*)d_ws;
  constexpr size_t OFF_FLAGS = 0;                            // 128 x 4B (pad 1K)
  constexpr size_t OFF_HBUF  = 1024;                         // 2*32*512*2 = 64 KB
  constexpr size_t OFF_PO    = OFF_HBUF + 65536;             // 32 MB
  constexpr size_t OFF_XB    = OFF_PO + 33554432;            // 64 MB bf16
  constexpr size_t OFF_W4XT  = OFF_XB + 67108864;            // 2 MB
  constexpr size_t OFF_W4HT  = OFF_W4XT + 2097152;           // 2 MB
  constexpr size_t OFF_BIAS  = OFF_W4HT + 2097152;           // 8 KB
  constexpr size_t OFF_G0    = OFF_BIAS + 8192;
  constexpr size_t TOT_F32   = OFF_G0 + (size_t)65536 * 2048 * 4;
  bool g32 = (ws_size >= TOT_F32);

  u32* flags     = (u32*)(ws + OFF_FLAGS);
  u16* h_buf     = (u16*)(ws + OFF_HBUF);
  float* po      = (float*)(ws + OFF_PO);
  u16* xb        = (u16*)(ws + OFF_XB);
  u16* w4xt      = (u16*)(ws + OFF_W4XT);
  u16* w4ht      = (u16*)(ws + OFF_W4HT);
  float* bias4   = (float*)(ws + OFF_BIAS);
  char* gates0   = ws + OFF_G0;

  // zero flags + h_buf every launch (determinism across graph replays)
  hipMemsetAsync(d_ws, 0, OFF_HBUF + 65536, stream);

  k_cast_x<<<16384, 256, 0, stream>>>(x, xb);
  k_pack_w<<<1025, 256, 0, stream>>>(Wxi, Whi, bi, Wxf, Whf, bfv, Wxo, Who, bo,
                                     Wxc, Whc, bc, w4xt, w4ht, bias4);
  if (g32) {
    k_gemm<1><<<8192, 256, 0, stream>>>(xb, w4xt, bias4, gates0);
    k_rnn<1><<<NWG, 256, 0, stream>>>(w4ht, gates0, Wd, h_buf, po, flags);
  } else {
    k_gemm<0><<<8192, 256, 0, stream>>>(xb, w4xt, bias4, gates0);
    k_rnn<0><<<NWG, 256, 0, stream>>>(w4ht, gates0, Wd, h_buf, po, flags);
  }
  k_reduce<<<256, 256, 0, stream>>>(po, bd, (float*)d_out);
}

// Round 9
// 11357.407 us; speedup vs baseline: 1.5328x; 1.5328x over previous
//
#include <hip/hip_runtime.h>
#include <cstdint>
#include <cstddef>

#define B_  32
#define T_  2048
#define D_  512
#define H_  512
#define NWG 32   // recurrent workgroups; each owns 16 h-cols = 64 gate-cols

typedef unsigned int   u32;
typedef unsigned short u16;
typedef u32   u32x4  __attribute__((ext_vector_type(4)));
typedef u32   u32x2  __attribute__((ext_vector_type(2)));
typedef float f32x4  __attribute__((ext_vector_type(4)));
typedef __bf16 bf16x8 __attribute__((ext_vector_type(8)));

__device__ __forceinline__ u16 f2bf(float f) {
  u32 u = __builtin_bit_cast(u32, f);
  u32 r = (u + 0x7fffu + ((u >> 16) & 1u)) >> 16;   // RNE
  return (u16)r;
}
__device__ __forceinline__ f32x4 g4_from_bf(u32x2 p) {
  f32x4 r;
  r[0] = __builtin_bit_cast(float, (p[0] & 0xffffu) << 16);
  r[1] = __builtin_bit_cast(float, (p[0] & 0xffff0000u));
  r[2] = __builtin_bit_cast(float, (p[1] & 0xffffu) << 16);
  r[3] = __builtin_bit_cast(float, (p[1] & 0xffff0000u));
  return r;
}
__device__ __forceinline__ float sigm(float x) {
  return __builtin_amdgcn_rcpf(1.0f + __expf(-x));
}
__device__ __forceinline__ float tanh_fast(float x) {
  return 1.0f - 2.0f * __builtin_amdgcn_rcpf(__expf(2.0f * x) + 1.0f);
}

// ---------------------------------------------------------------------------
// K1: cast x [B][T][D] fp32 -> xb bf16, time-major rows m = t*32 + b
// ---------------------------------------------------------------------------
__global__ __launch_bounds__(256) void k_cast_x(const float* __restrict__ x,
                                                u16* __restrict__ xb) {
  long i = (long)blockIdx.x * 256 + threadIdx.x;
  int  dc = (int)(i & 63);
  long m  = i >> 6;
  int  t  = (int)(m >> 5), b = (int)(m & 31);
  const float* src = x + ((long)b * T_ + t) * D_ + (dc << 3);
  f32x4 a = *(const f32x4*)(src);
  f32x4 c = *(const f32x4*)(src + 4);
  u32x4 pv;
  pv[0] = (u32)f2bf(a[0]) | ((u32)f2bf(a[1]) << 16);
  pv[1] = (u32)f2bf(a[2]) | ((u32)f2bf(a[3]) << 16);
  pv[2] = (u32)f2bf(c[0]) | ((u32)f2bf(c[1]) << 16);
  pv[3] = (u32)f2bf(c[2]) | ((u32)f2bf(c[3]) << 16);
  *(u32x4*)(xb + (m << 9) + (dc << 3)) = pv;
}

// ---------------------------------------------------------------------------
// K2: pack weights transposed + gate-interleaved. col n = hcol*4 + gate.
// ---------------------------------------------------------------------------
__global__ __launch_bounds__(256) void k_pack_w(
    const float* __restrict__ Wxi, const float* __restrict__ Whi, const float* __restrict__ bi,
    const float* __restrict__ Wxf, const float* __restrict__ Whf, const float* __restrict__ bfv,
    const float* __restrict__ Wxo, const float* __restrict__ Who, const float* __restrict__ bo,
    const float* __restrict__ Wxc, const float* __restrict__ Whc, const float* __restrict__ bc,
    u16* __restrict__ w4xt, u16* __restrict__ w4ht, float* __restrict__ bias4) {
  int blk = blockIdx.x, tid = threadIdx.x;
  if (blk == 1024) {
    for (int i = tid; i < 2048; i += 256) {
      int hcol = i >> 2, g = i & 3;
      const float* bsrc = (g == 0 ? bi : g == 1 ? bfv : g == 2 ? bo : bc);
      bias4[i] = bsrc[hcol];
    }
    return;
  }
  bool isx = (blk < 512);
  long s = (long)(isx ? blk : blk - 512) * 256 + tid;
  int n = (int)(s >> 6);
  int c = (int)(s & 63);
  int hcol = n >> 2, g = n & 3;
  const float* W = isx ? (g == 0 ? Wxi : g == 1 ? Wxf : g == 2 ? Wxo : Wxc)
                       : (g == 0 ? Whi : g == 1 ? Whf : g == 2 ? Who : Whc);
  u16* dst = (isx ? w4xt : w4ht) + ((long)n << 9) + (c << 3);
#pragma unroll
  for (int j = 0; j < 8; j++) dst[j] = f2bf(W[(long)((c << 3) + j) * H_ + hcol]);
}

// ---------------------------------------------------------------------------
// K3: GEMM gates0[m][n] = sum_k xb[m][k]*w4xt[n][k] + bias4[n]
// ---------------------------------------------------------------------------
template <int G32>
__global__ __launch_bounds__(256) void k_gemm(const u16* __restrict__ xb,
                                              const u16* __restrict__ w4xt,
                                              const float* __restrict__ bias4,
                                              char* __restrict__ gates0) {
  __shared__ __align__(16) unsigned char As[128 * 32 * 2];
  __shared__ __align__(16) unsigned char Bs[128 * 32 * 2];
  int tid = threadIdx.x;
  int bm = blockIdx.x & 511;
  int bn = blockIdx.x >> 9;
  long m0 = (long)bm << 7;
  int  n0 = bn << 7;
  int wv = tid >> 6, lane = tid & 63;
  int wr = wv >> 1, wc = wv & 1;
  int lr = lane & 15, lc = lane >> 4;

  f32x4 acc[4][4];
#pragma unroll
  for (int i = 0; i < 4; i++)
#pragma unroll
    for (int j = 0; j < 4; j++) acc[i][j] = (f32x4){0.f, 0.f, 0.f, 0.f};

  for (int kt = 0; kt < 16; kt++) {
#pragma unroll
    for (int h = 0; h < 2; h++) {
      int s = h * 256 + tid;
      int row = s >> 2, ch = s & 3;
      u32x4 va = *(const u32x4*)(xb + ((m0 + row) << 9) + (kt << 5) + (ch << 3));
      *(u32x4*)(As + (((row << 6) + (ch << 4)) ^ ((row & 3) << 4))) = va;
      u32x4 vb = *(const u32x4*)(w4xt + (((long)n0 + row) << 9) + (kt << 5) + (ch << 3));
      *(u32x4*)(Bs + (((row << 6) + (ch << 4)) ^ ((row & 3) << 4))) = vb;
    }
    __syncthreads();
    bf16x8 af[4], bfr[4];
#pragma unroll
    for (int mi = 0; mi < 4; mi++) {
      int row = (wr << 6) + (mi << 4) + lr;
      af[mi] = __builtin_bit_cast(bf16x8,
          *(const u32x4*)(As + (((row << 6) + (lc << 4)) ^ ((row & 3) << 4))));
    }
#pragma unroll
    for (int ni = 0; ni < 4; ni++) {
      int row = (wc << 6) + (ni << 4) + lr;
      bfr[ni] = __builtin_bit_cast(bf16x8,
          *(const u32x4*)(Bs + (((row << 6) + (lc << 4)) ^ ((row & 3) << 4))));
    }
#pragma unroll
    for (int mi = 0; mi < 4; mi++)
#pragma unroll
      for (int ni = 0; ni < 4; ni++)
        acc[mi][ni] = __builtin_amdgcn_mfma_f32_16x16x32_bf16(af[mi], bfr[ni], acc[mi][ni], 0, 0, 0);
    __syncthreads();
  }
#pragma unroll
  for (int mi = 0; mi < 4; mi++) {
#pragma unroll
    for (int ni = 0; ni < 4; ni++) {
      int col = n0 + (wc << 6) + (ni << 4) + lr;
      float bias = bias4[col];
#pragma unroll
      for (int r = 0; r < 4; r++) {
        long row = m0 + (wr << 6) + (mi << 4) + (lc << 2) + r;
        float v = acc[mi][ni][r] + bias;
        if constexpr (G32) ((float*)gates0)[(row << 11) + col] = v;
        else               ((u16*)gates0)[(row << 11) + col] = f2bf(v);
      }
    }
  }
}

// ---------------------------------------------------------------------------
// K4: persistent recurrent kernel. r4's proven drain->flag->poll->load
// protocol with the three measured leaks removed:
//  - per-wave flags (128, packed 512B; r6-proven) published after each wave's
//    own vmcnt(0) h-store drain; single-poller wave 0 + __syncthreads bcast.
//  - gates0 loads issued AFTER the readiness barrier (drain overlaps h-load
//    vmcnt(0) instead of sitting inside the poll).
//  - Wh slice in LDS (r1-proven staging/swizzle) instead of the VGPR fiction.
// ---------------------------------------------------------------------------
template <int G32>
__global__ __launch_bounds__(256, 1) void k_rnn(const u16* __restrict__ w4ht,
                                                const char* __restrict__ gates0,
                                                const float* __restrict__ wd,
                                                u16* __restrict__ h_buf,   // [2][32][512] bf16
                                                float* __restrict__ po,    // [T][NWG][32]
                                                u32* __restrict__ flags) { // [128] packed u32
  __shared__ __align__(16) unsigned char whs[64 * 1024];   // Wh slice, 64 KB
  __shared__ __align__(16) float G_all[32 * 64];           // [batch][WG gate-col]

  const int tid = threadIdx.x;
  const int w = blockIdx.x;
  const int wv = tid >> 6, lane = tid & 63;
  const int lr = lane & 15, lc = lane >> 4;
  const int hhalf = wv >> 1;           // batch half: rows hhalf*16 + 0..15
  const int wcol  = wv & 1;            // col half of the 64 WG gate-cols
  const int ncol0 = (wcol << 5) + lr;  // WG-local gate col of acc0 (0..63)
  const int ncol1 = ncol0 + 16;

  // stage Wh slice -> LDS (row = WG-local gate-col, XOR-swizzled; r1-proven)
#pragma unroll 4
  for (int i = 0; i < 16; i++) {
    int s = i * 256 + tid;
    int n = s >> 6, c = s & 63;
    u32x4 v = *(const u32x4*)(w4ht + ((long)((w << 6) + n) << 9) + (c << 3));
    *(u32x4*)(whs + (((n << 10) + (c << 4)) ^ ((n & 7) << 4))) = v;
  }
  __syncthreads();

  const int pb = tid >> 4;   // 0..15 (batch row; also +16)
  const int jj = tid & 15;   // 0..15 (h-col within this WG's 16)
  float c0 = 0.f, c1 = 0.f;
  const float wdr = wd[(w << 4) + jj];   // Wd element for this lane's h-col

  const u32 hbase = (u32)(((hhalf << 4) + lr) << 10);   // A-frag row base (bytes)
  const u32 poll_off = (u32)(lane << 3);                // flags[2*lane..+1]
  const u32 flag_off = (u32)(((w << 2) + wv) << 2);     // flags[w*4+wv]
  const u32 st0 = (u32)((((pb) << 9) + (w << 4) + jj) << 1);
  const u32 st1 = (u32)((((pb + 16) << 9) + (w << 4) + jj) << 1);
  const u32 b0base = (u32)(ncol0 << 10), b0swz = (u32)((ncol0 & 7) << 4);
  const u32 b1base = (u32)(ncol1 << 10), b1swz = (u32)((ncol1 & 7) << 4);

#pragma unroll 1
  for (int t = 0; t < T_; t++) {
    const u16* hb_cur = h_buf + ((t & 1) << 14);
    u16* hb_nxt = h_buf + (((t + 1) & 1) << 14);

    // ---- readiness: wave 0 polls all 128 per-wave flags, then broadcast
    if (t > 0) {
      if (wv == 0) {
        u32x2 fv;
        do {
          asm volatile("global_load_dwordx2 %0, %1, %2 sc1\n\ts_waitcnt vmcnt(0)"
                       : "=v"(fv) : "v"(poll_off), "s"(flags) : "memory");
        } while (!__all((fv[0] >= (u32)t) && (fv[1] >= (u32)t)));
      }
      __syncthreads();   // broadcast "h_t ready" to all waves
    }

    // ---- gates0 loads for THIS step (plain cached; drain overlaps h loads)
    f32x4 gfa, gfb; u32x2 gba, gbb;
    {
      long i0 = ((long)t * 32 + pb) * 2048 + (w << 6) + (jj << 2);
      long i1 = i0 + 16 * 2048;
      if constexpr (G32) {
        gfa = *(const f32x4*)((const float*)gates0 + i0);
        gfb = *(const f32x4*)((const float*)gates0 + i1);
      } else {
        gba = *(const u32x2*)((const u16*)gates0 + i0);
        gbb = *(const u32x2*)((const u16*)gates0 + i1);
      }
    }

    // ---- h_t straight into registers, device scope (16 x 16B per lane)
    u32x4 ha[16];
#pragma unroll
    for (int kk = 0; kk < 16; kk++) {
      asm volatile("global_load_dwordx4 %0, %1, %2 sc1"
                   : "=v"(ha[kk]) : "v"(hbase + (u32)(kk << 6) + (u32)(lc << 4)),
                     "s"(hb_cur));
    }
    asm volatile("s_waitcnt vmcnt(0)" ::: "memory");
    __builtin_amdgcn_sched_barrier(0);   // rule #18: MFMA must not hoist past wait

    // ---- G = h @ Wh_slice (A=h rows=batch, B=Wh from LDS; r4-verified)
    f32x4 acc0 = {0.f,0.f,0.f,0.f}, acc1 = {0.f,0.f,0.f,0.f};
#pragma unroll
    for (int kk = 0; kk < 16; kk++) {
      u32 ko = (u32)((kk << 6) + (lc << 4));
      bf16x8 a  = __builtin_bit_cast(bf16x8, ha[kk]);
      bf16x8 b0 = __builtin_bit_cast(bf16x8, *(const u32x4*)(whs + ((b0base + ko) ^ b0swz)));
      bf16x8 b1 = __builtin_bit_cast(bf16x8, *(const u32x4*)(whs + ((b1base + ko) ^ b1swz)));
      acc0 = __builtin_amdgcn_mfma_f32_16x16x32_bf16(a, b0, acc0, 0, 0, 0);
      acc1 = __builtin_amdgcn_mfma_f32_16x16x32_bf16(a, b1, acc1, 0, 0, 0);
    }
#pragma unroll
    for (int r = 0; r < 4; r++) {
      int grow = (hhalf << 4) + (lc << 2) + r;
      G_all[(grow << 6) + ncol0] = acc0[r];
      G_all[(grow << 6) + ncol1] = acc1[r];
    }
    __syncthreads();   // bar1: G ready

    // ---- LSTM cell (r4 verbatim); h stores device-scope
    float hnA, hnB;
    {
      f32x4 g0a, g0b;
      if constexpr (G32) { g0a = gfa; g0b = gfb; }
      else { g0a = g4_from_bf(gba); g0b = g4_from_bf(gbb); }

      f32x4 gv = *(const f32x4*)(&G_all[(pb << 6) + (jj << 2)]);
      float I = sigm(gv[0] + g0a[0]);
      float F = sigm(gv[1] + g0a[1]);
      float O = sigm(gv[2] + g0a[2]);
      float Ct = tanh_fast(gv[3] + g0a[3]);
      float cn = F * c0 + I * Ct;
      hnA = O * tanh_fast(cn);
      c0 = cn;
      u32 hv0 = (u32)f2bf(hnA);
      asm volatile("global_store_short %0, %1, %2 sc1"
                   :: "v"(st0), "v"(hv0), "s"(hb_nxt) : "memory");

      f32x4 gw = *(const f32x4*)(&G_all[((pb + 16) << 6) + (jj << 2)]);
      float I2 = sigm(gw[0] + g0b[0]);
      float F2 = sigm(gw[1] + g0b[1]);
      float O2 = sigm(gw[2] + g0b[2]);
      float Ct2 = tanh_fast(gw[3] + g0b[3]);
      float cn2 = F2 * c1 + I2 * Ct2;
      hnB = O2 * tanh_fast(cn2);
      c1 = cn2;
      u32 hv1 = (u32)f2bf(hnB);
      asm volatile("global_store_short %0, %1, %2 sc1"
                   :: "v"(st1), "v"(hv1), "s"(hb_nxt) : "memory");
    }

    // ---- per-wave drain + flag publish (r6-proven protocol)
    asm volatile("s_waitcnt vmcnt(0)" ::: "memory");
    __builtin_amdgcn_sched_barrier(0);
    if (lane == 0) {
      u32 fval = (u32)(t + 1);
      asm volatile("global_store_dword %0, %1, %2 sc1"
                   :: "v"(flag_off), "v"(fval), "s"(flags) : "memory");
    }

    // ---- Wd partial, in-wave reduce over jj (off critical path, no barrier)
    float pA = hnA * wdr, pB = hnB * wdr;
    pA += __shfl_xor(pA, 1); pA += __shfl_xor(pA, 2);
    pA += __shfl_xor(pA, 4); pA += __shfl_xor(pA, 8);
    pB += __shfl_xor(pB, 1); pB += __shfl_xor(pB, 2);
    pB += __shfl_xor(pB, 4); pB += __shfl_xor(pB, 8);
    if (jj == 0) {
      float* pp = po + ((long)t * NWG + w) * 32;
      pp[pb] = pA;
      pp[pb + 16] = pB;
    }
  }
}

// ---------------------------------------------------------------------------
// K5: out[b,t] = sum_w po[t][w][b] + bd
// ---------------------------------------------------------------------------
__global__ __launch_bounds__(256) void k_reduce(const float* __restrict__ po,
                                                const float* __restrict__ bd,
                                                float* __restrict__ out) {
  int tid = threadIdx.x;
  int b = tid & 31, tl = tid >> 5;
  int t = blockIdx.x * 8 + tl;
  float s = bd[0];
#pragma unroll
  for (int w = 0; w < NWG; w++) s += po[((long)t * NWG + w) * 32 + b];
  out[(long)b * T_ + t] = s;
}

// ---------------------------------------------------------------------------
extern "C" void kernel_launch(void* const* d_in, const int* in_sizes, int n_in,
                              void* d_out, int out_size, void* d_ws, size_t ws_size,
                              hipStream_t stream) {
  const float* x   = (const float*)d_in[0];
  const float* Wxi = (const float*)d_in[1];
  const float* Whi = (const float*)d_in[2];
  const float* bi  = (const float*)d_in[3];
  const float* Wxf = (const float*)d_in[4];
  const float* Whf = (const float*)d_in[5];
  const float* bfv = (const float*)d_in[6];
  const float* Wxo = (const float*)d_in[7];
  const float* Who = (const float*)d_in[8];
  const float* bo  = (const float*)d_in[9];
  const float* Wxc = (const float*)d_in[10];
  const float* Whc = (const float*)d_in[11];
  const float* bc  = (const float*)d_in[12];
  const float* Wd  = (const float*)d_in[13];
  const float* bd  = (const float*)d_in[14];

  char* ws = (char*)d_ws;
  constexpr size_t OFF_FLAGS = 0;                            // 128 x 4B (pad 2K)
  constexpr size_t OFF_HBUF  = 2048;                         // 2*32*512*2 = 64 KB
  constexpr size_t OFF_PO    = OFF_HBUF + 65536;             // 8 MB
  constexpr size_t OFF_XB    = OFF_PO + 8388608;             // 64 MB bf16
  constexpr size_t OFF_W4XT  = OFF_XB + 67108864;            // 2 MB
  constexpr size_t OFF_W4HT  = OFF_W4XT + 2097152;           // 2 MB
  constexpr size_t OFF_BIAS  = OFF_W4HT + 2097152;           // 8 KB
  constexpr size_t OFF_G0    = OFF_BIAS + 8192;
  constexpr size_t TOT_F32   = OFF_G0 + (size_t)65536 * 2048 * 4;
  bool g32 = (ws_size >= TOT_F32);

  u32* flags     = (u32*)(ws + OFF_FLAGS);
  u16* h_buf     = (u16*)(ws + OFF_HBUF);
  float* po      = (float*)(ws + OFF_PO);
  u16* xb        = (u16*)(ws + OFF_XB);
  u16* w4xt      = (u16*)(ws + OFF_W4XT);
  u16* w4ht      = (u16*)(ws + OFF_W4HT);
  float* bias4   = (float*)(ws + OFF_BIAS);
  char* gates0   = ws + OFF_G0;

  // zero flags + h_buf every launch (determinism across graph replays)
  hipMemsetAsync(d_ws, 0, OFF_PO, stream);

  k_cast_x<<<16384, 256, 0, stream>>>(x, xb);
  k_pack_w<<<1025, 256, 0, stream>>>(Wxi, Whi, bi, Wxf, Whf, bfv, Wxo, Who, bo,
                                     Wxc, Whc, bc, w4xt, w4ht, bias4);
  if (g32) {
    k_gemm<1><<<8192, 256, 0, stream>>>(xb, w4xt, bias4, gates0);
    k_rnn<1><<<NWG, 256, 0, stream>>>(w4ht, gates0, Wd, h_buf, po, flags);
  } else {
    k_gemm<0><<<8192, 256, 0, stream>>>(xb, w4xt, bias4, gates0);
    k_rnn<0><<<NWG, 256, 0, stream>>>(w4ht, gates0, Wd, h_buf, po, flags);
  }
  k_reduce<<<256, 256, 0, stream>>>(po, bd, (float*)d_out);
}

// Round 11
// 9169.839 us; speedup vs baseline: 1.8984x; 1.2386x over previous
//
#include <hip/hip_runtime.h>
#include <cstdint>
#include <cstddef>

#define B_  32
#define T_  2048
#define D_  512
#define H_  512
#define NWG 32   // recurrent workgroups; each owns 16 h-cols = 64 gate-cols

typedef unsigned int   u32;
typedef unsigned short u16;
typedef u32   u32x4  __attribute__((ext_vector_type(4)));
typedef u32   u32x2  __attribute__((ext_vector_type(2)));
typedef float f32x4  __attribute__((ext_vector_type(4)));
typedef __bf16 bf16x8 __attribute__((ext_vector_type(8)));

__device__ __forceinline__ u16 f2bf(float f) {
  u32 u = __builtin_bit_cast(u32, f);
  u32 r = (u + 0x7fffu + ((u >> 16) & 1u)) >> 16;   // RNE
  return (u16)r;
}
__device__ __forceinline__ f32x4 g4_from_bf(u32x2 p) {
  f32x4 r;
  r[0] = __builtin_bit_cast(float, (p[0] & 0xffffu) << 16);
  r[1] = __builtin_bit_cast(float, (p[0] & 0xffff0000u));
  r[2] = __builtin_bit_cast(float, (p[1] & 0xffffu) << 16);
  r[3] = __builtin_bit_cast(float, (p[1] & 0xffff0000u));
  return r;
}
// fast sigmoid/tanh via v_exp + v_rcp (validated r9/r10: absmax unchanged)
__device__ __forceinline__ float sigm(float x) {
  return __builtin_amdgcn_rcpf(1.0f + __expf(-x));
}
__device__ __forceinline__ float tanh_fast(float x) {
  return 1.0f - 2.0f * __builtin_amdgcn_rcpf(__expf(2.0f * x) + 1.0f);
}

// ---------------------------------------------------------------------------
// K1: cast x [B][T][D] fp32 -> xb bf16, time-major rows m = t*32 + b
// ---------------------------------------------------------------------------
__global__ __launch_bounds__(256) void k_cast_x(const float* __restrict__ x,
                                                u16* __restrict__ xb) {
  long i = (long)blockIdx.x * 256 + threadIdx.x;
  int  dc = (int)(i & 63);
  long m  = i >> 6;
  int  t  = (int)(m >> 5), b = (int)(m & 31);
  const float* src = x + ((long)b * T_ + t) * D_ + (dc << 3);
  f32x4 a = *(const f32x4*)(src);
  f32x4 c = *(const f32x4*)(src + 4);
  u32x4 pv;
  pv[0] = (u32)f2bf(a[0]) | ((u32)f2bf(a[1]) << 16);
  pv[1] = (u32)f2bf(a[2]) | ((u32)f2bf(a[3]) << 16);
  pv[2] = (u32)f2bf(c[0]) | ((u32)f2bf(c[1]) << 16);
  pv[3] = (u32)f2bf(c[2]) | ((u32)f2bf(c[3]) << 16);
  *(u32x4*)(xb + (m << 9) + (dc << 3)) = pv;
}

// ---------------------------------------------------------------------------
// K2: pack weights transposed + gate-interleaved. col n = hcol*4 + gate.
// ---------------------------------------------------------------------------
__global__ __launch_bounds__(256) void k_pack_w(
    const float* __restrict__ Wxi, const float* __restrict__ Whi, const float* __restrict__ bi,
    const float* __restrict__ Wxf, const float* __restrict__ Whf, const float* __restrict__ bfv,
    const float* __restrict__ Wxo, const float* __restrict__ Who, const float* __restrict__ bo,
    const float* __restrict__ Wxc, const float* __restrict__ Whc, const float* __restrict__ bc,
    u16* __restrict__ w4xt, u16* __restrict__ w4ht, float* __restrict__ bias4) {
  int blk = blockIdx.x, tid = threadIdx.x;
  if (blk == 1024) {
    for (int i = tid; i < 2048; i += 256) {
      int hcol = i >> 2, g = i & 3;
      const float* bsrc = (g == 0 ? bi : g == 1 ? bfv : g == 2 ? bo : bc);
      bias4[i] = bsrc[hcol];
    }
    return;
  }
  bool isx = (blk < 512);
  long s = (long)(isx ? blk : blk - 512) * 256 + tid;
  int n = (int)(s >> 6);
  int c = (int)(s & 63);
  int hcol = n >> 2, g = n & 3;
  const float* W = isx ? (g == 0 ? Wxi : g == 1 ? Wxf : g == 2 ? Wxo : Wxc)
                       : (g == 0 ? Whi : g == 1 ? Whf : g == 2 ? Who : Whc);
  u16* dst = (isx ? w4xt : w4ht) + ((long)n << 9) + (c << 3);
#pragma unroll
  for (int j = 0; j < 8; j++) dst[j] = f2bf(W[(long)((c << 3) + j) * H_ + hcol]);
}

// ---------------------------------------------------------------------------
// K3: GEMM gates0[m][n] = sum_k xb[m][k]*w4xt[n][k] + bias4[n]
// ---------------------------------------------------------------------------
template <int G32>
__global__ __launch_bounds__(256) void k_gemm(const u16* __restrict__ xb,
                                              const u16* __restrict__ w4xt,
                                              const float* __restrict__ bias4,
                                              char* __restrict__ gates0) {
  __shared__ __align__(16) unsigned char As[128 * 32 * 2];
  __shared__ __align__(16) unsigned char Bs[128 * 32 * 2];
  int tid = threadIdx.x;
  int bm = blockIdx.x & 511;
  int bn = blockIdx.x >> 9;
  long m0 = (long)bm << 7;
  int  n0 = bn << 7;
  int wv = tid >> 6, lane = tid & 63;
  int wr = wv >> 1, wc = wv & 1;
  int lr = lane & 15, lc = lane >> 4;

  f32x4 acc[4][4];
#pragma unroll
  for (int i = 0; i < 4; i++)
#pragma unroll
    for (int j = 0; j < 4; j++) acc[i][j] = (f32x4){0.f, 0.f, 0.f, 0.f};

  for (int kt = 0; kt < 16; kt++) {
#pragma unroll
    for (int h = 0; h < 2; h++) {
      int s = h * 256 + tid;
      int row = s >> 2, ch = s & 3;
      u32x4 va = *(const u32x4*)(xb + ((m0 + row) << 9) + (kt << 5) + (ch << 3));
      *(u32x4*)(As + (((row << 6) + (ch << 4)) ^ ((row & 3) << 4))) = va;
      u32x4 vb = *(const u32x4*)(w4xt + (((long)n0 + row) << 9) + (kt << 5) + (ch << 3));
      *(u32x4*)(Bs + (((row << 6) + (ch << 4)) ^ ((row & 3) << 4))) = vb;
    }
    __syncthreads();
    bf16x8 af[4], bfr[4];
#pragma unroll
    for (int mi = 0; mi < 4; mi++) {
      int row = (wr << 6) + (mi << 4) + lr;
      af[mi] = __builtin_bit_cast(bf16x8,
          *(const u32x4*)(As + (((row << 6) + (lc << 4)) ^ ((row & 3) << 4))));
    }
#pragma unroll
    for (int ni = 0; ni < 4; ni++) {
      int row = (wc << 6) + (ni << 4) + lr;
      bfr[ni] = __builtin_bit_cast(bf16x8,
          *(const u32x4*)(Bs + (((row << 6) + (lc << 4)) ^ ((row & 3) << 4))));
    }
#pragma unroll
    for (int mi = 0; mi < 4; mi++)
#pragma unroll
      for (int ni = 0; ni < 4; ni++)
        acc[mi][ni] = __builtin_amdgcn_mfma_f32_16x16x32_bf16(af[mi], bfr[ni], acc[mi][ni], 0, 0, 0);
    __syncthreads();
  }
#pragma unroll
  for (int mi = 0; mi < 4; mi++) {
#pragma unroll
    for (int ni = 0; ni < 4; ni++) {
      int col = n0 + (wc << 6) + (ni << 4) + lr;
      float bias = bias4[col];
#pragma unroll
      for (int r = 0; r < 4; r++) {
        long row = m0 + (wr << 6) + (mi << 4) + (lc << 2) + r;
        float v = acc[mi][ni][r] + bias;
        if constexpr (G32) ((float*)gates0)[(row << 11) + col] = v;
        else               ((u16*)gates0)[(row << 11) + col] = f2bf(v);
      }
    }
  }
}

// ---------------------------------------------------------------------------
// K4: persistent recurrent kernel — r4's proven protocol VERBATIM
// (grid=32, device-scope sc1 h/flags, gates-before-poll, all-wave poll,
//  drain->barrier->flag publish) with three validated micro-deltas:
//  tanh_fast (r9/r10 numerics), in-wave Wd partial (r9), flag prefetch
//  (monotonic flags -> stale prefetch is safe, just re-polls).
// ---------------------------------------------------------------------------
template <int G32>
__global__ __launch_bounds__(256, 1) void k_rnn(const u16* __restrict__ w4ht,
                                                const char* __restrict__ gates0,
                                                const float* __restrict__ wd,
                                                u16* __restrict__ h_buf,   // [2][32][512] bf16
                                                float* __restrict__ po,    // [T][NWG][32]
                                                u32* __restrict__ flags) { // [NWG] @64B stride
  __shared__ __align__(16) float G_all[32 * 64];   // [batch 32][gate-col 64]

  const int tid = threadIdx.x;
  const int w = blockIdx.x;
  const int wv = tid >> 6, lane = tid & 63;
  const int lr = lane & 15, lc = lane >> 4;
  const int hhalf = wv >> 1;           // batch half: rows hhalf*16 + 0..15
  const int wcol  = wv & 1;            // col half: WG-local gate cols
  const int ncol0 = (wcol << 5) + lr;  // WG-local gate col of acc0 (0..63)
  const int ncol1 = ncol0 + 16;

  // B fragments in registers (r4 verbatim): 2 tiles x 16 k-frags
  u32x4 wfr0[16], wfr1[16];
  {
    const u16* wb = w4ht + ((long)(w << 6) << 9);
#pragma unroll
    for (int kk = 0; kk < 16; kk++) {
      wfr0[kk] = *(const u32x4*)(wb + ((long)ncol0 << 9) + (kk << 5) + (lc << 3));
      wfr1[kk] = *(const u32x4*)(wb + ((long)ncol1 << 9) + (kk << 5) + (lc << 3));
    }
  }

  const int pb = tid >> 4;   // 0..15 (batch row; also +16)
  const int jj = tid & 15;   // 0..15 (h-col within this WG's 16)
  float c0 = 0.f, c1 = 0.f;
  const float wdr = wd[(w << 4) + jj];   // Wd element for this lane's h-col

  const int arow = (hhalf << 4) + lr;              // A row this lane feeds
  const u32 hbase = (u32)(arow << 10);             // byte base in h buffer
  const u32 poll_off = (u32)((lane & 31) << 6);    // 64B-strided flags
  const u32 flag_off = (u32)(w << 6);
  const u32 st0 = (u32)((((pb) << 9) + (w << 4) + jj) << 1);
  const u32 st1 = (u32)((((pb + 16) << 9) + (w << 4) + jj) << 1);

  u32 fpre = 0;   // prefetched flag value (issued at end of previous step)

#pragma unroll 1
  for (int t = 0; t < T_; t++) {
    const u16* hb_cur = h_buf + ((t & 1) << 14);
    u16* hb_nxt = h_buf + (((t + 1) & 1) << 14);

    // phase A: issue this step's gates0 loads (plain, cached; their HBM
    // latency drains inside the poll's vmcnt(0) — r4-proven arrangement)
    f32x4 gfa, gfb; u32x2 gba, gbb;
    {
      long i0 = ((long)t * 32 + pb) * 2048 + (w << 6) + (jj << 2);
      long i1 = i0 + 16 * 2048;
      if constexpr (G32) {
        gfa = *(const f32x4*)((const float*)gates0 + i0);
        gfb = *(const f32x4*)((const float*)gates0 + i1);
      } else {
        gba = *(const u32x2*)((const u16*)gates0 + i0);
        gbb = *(const u32x2*)((const u16*)gates0 + i1);
      }
    }

    // phase B: check prefetched flags first; fall back to the r4 poll loop
    if (t > 0) {
      asm volatile("s_waitcnt vmcnt(0)" ::: "memory");   // fpre + gates resident
      if (!__all(fpre >= (u32)t)) {
        u32 fv;
        do {
          asm volatile("global_load_dword %0, %1, %2 sc1\n\ts_waitcnt vmcnt(0)"
                       : "=v"(fv) : "v"(poll_off), "s"(flags) : "memory");
        } while (!__all(fv >= (u32)t));
      }
    }

    // phase C: h_t straight into registers, device scope (16 x 16B per lane)
    u32x4 ha[16];
#pragma unroll
    for (int kk = 0; kk < 16; kk++) {
      asm volatile("global_load_dwordx4 %0, %1, %2 sc1"
                   : "=v"(ha[kk]) : "v"(hbase + (u32)(kk << 6) + (u32)(lc << 4)),
                     "s"(hb_cur));
    }
    asm volatile("s_waitcnt vmcnt(0)" ::: "memory");
    __builtin_amdgcn_sched_barrier(0);   // rule #18: MFMA must not hoist past wait

    // phase C2: G = h @ Wh_slice; wave = (batch-half, col-half)  [r4-verified]
    f32x4 acc0 = {0.f, 0.f, 0.f, 0.f}, acc1 = {0.f, 0.f, 0.f, 0.f};
#pragma unroll
    for (int kk = 0; kk < 16; kk++) {
      bf16x8 a = __builtin_bit_cast(bf16x8, ha[kk]);
      acc0 = __builtin_amdgcn_mfma_f32_16x16x32_bf16(a, __builtin_bit_cast(bf16x8, wfr0[kk]), acc0, 0, 0, 0);
      acc1 = __builtin_amdgcn_mfma_f32_16x16x32_bf16(a, __builtin_bit_cast(bf16x8, wfr1[kk]), acc1, 0, 0, 0);
    }
#pragma unroll
    for (int r = 0; r < 4; r++) {
      int grow = (hhalf << 4) + (lc << 2) + r;
      G_all[(grow << 6) + ncol0] = acc0[r];
      G_all[(grow << 6) + ncol1] = acc1[r];
    }
    __syncthreads();   // bar1: G ready

    // phase D: pointwise LSTM cell; c in registers; h stores device-scope
    float hnA, hnB;
    {
      f32x4 g0a, g0b;
      if constexpr (G32) { g0a = gfa; g0b = gfb; }
      else { g0a = g4_from_bf(gba); g0b = g4_from_bf(gbb); }

      f32x4 gv = *(const f32x4*)(&G_all[(pb << 6) + (jj << 2)]);
      float I = sigm(gv[0] + g0a[0]);
      float F = sigm(gv[1] + g0a[1]);
      float O = sigm(gv[2] + g0a[2]);
      float Ct = tanh_fast(gv[3] + g0a[3]);
      float cn = F * c0 + I * Ct;
      hnA = O * tanh_fast(cn);
      c0 = cn;
      u32 hv0 = (u32)f2bf(hnA);
      asm volatile("global_store_short %0, %1, %2 sc1"
                   :: "v"(st0), "v"(hv0), "s"(hb_nxt) : "memory");

      f32x4 gw = *(const f32x4*)(&G_all[((pb + 16) << 6) + (jj << 2)]);
      float I2 = sigm(gw[0] + g0b[0]);
      float F2 = sigm(gw[1] + g0b[1]);
      float O2 = sigm(gw[2] + g0b[2]);
      float Ct2 = tanh_fast(gw[3] + g0b[3]);
      float cn2 = F2 * c1 + I2 * Ct2;
      hnB = O2 * tanh_fast(cn2);
      c1 = cn2;
      u32 hv1 = (u32)f2bf(hnB);
      asm volatile("global_store_short %0, %1, %2 sc1"
                   :: "v"(st1), "v"(hv1), "s"(hb_nxt) : "memory");
    }

    // drain own h stores, sync WG (=> all waves drained), publish flag (r4)
    asm volatile("s_waitcnt vmcnt(0)" ::: "memory");
    __syncthreads();
    if (tid == 0) {
      u32 fval = (u32)(t + 1);
      asm volatile("global_store_dword %0, %1, %2 sc1"
                   :: "v"(flag_off), "v"(fval), "s"(flags) : "memory");
    }

    // prefetch next step's flags (monotonic: stale value just re-polls)
    asm volatile("global_load_dword %0, %1, %2 sc1"
                 : "=v"(fpre) : "v"(poll_off), "s"(flags));

    // phase E: Wd partial via in-wave shfl reduce over jj (r9-validated)
    float pA = hnA * wdr, pB = hnB * wdr;
    pA += __shfl_xor(pA, 1); pA += __shfl_xor(pA, 2);
    pA += __shfl_xor(pA, 4); pA += __shfl_xor(pA, 8);
    pB += __shfl_xor(pB, 1); pB += __shfl_xor(pB, 2);
    pB += __shfl_xor(pB, 4); pB += __shfl_xor(pB, 8);
    if (jj == 0) {
      float* pp = po + ((long)t * NWG + w) * 32;
      pp[pb] = pA;
      pp[pb + 16] = pB;
    }
  }
}

// ---------------------------------------------------------------------------
// K5: out[b,t] = sum_w po[t][w][b] + bd
// ---------------------------------------------------------------------------
__global__ __launch_bounds__(256) void k_reduce(const float* __restrict__ po,
                                                const float* __restrict__ bd,
                                                float* __restrict__ out) {
  int tid = threadIdx.x;
  int b = tid & 31, tl = tid >> 5;
  int t = blockIdx.x * 8 + tl;
  float s = bd[0];
#pragma unroll
  for (int w = 0; w < NWG; w++) s += po[((long)t * NWG + w) * 32 + b];
  out[(long)b * T_ + t] = s;
}

// ---------------------------------------------------------------------------
extern "C" void kernel_launch(void* const* d_in, const int* in_sizes, int n_in,
                              void* d_out, int out_size, void* d_ws, size_t ws_size,
                              hipStream_t stream) {
  const float* x   = (const float*)d_in[0];
  const float* Wxi = (const float*)d_in[1];
  const float* Whi = (const float*)d_in[2];
  const float* bi  = (const float*)d_in[3];
  const float* Wxf = (const float*)d_in[4];
  const float* Whf = (const float*)d_in[5];
  const float* bfv = (const float*)d_in[6];
  const float* Wxo = (const float*)d_in[7];
  const float* Who = (const float*)d_in[8];
  const float* bo  = (const float*)d_in[9];
  const float* Wxc = (const float*)d_in[10];
  const float* Whc = (const float*)d_in[11];
  const float* bc  = (const float*)d_in[12];
  const float* Wd  = (const float*)d_in[13];
  const float* bd  = (const float*)d_in[14];

  char* ws = (char*)d_ws;
  constexpr size_t OFF_FLAGS = 0;                            // 32 x 64B = 2 KB
  constexpr size_t OFF_HBUF  = 2048;                         // 2*32*512*2 = 64 KB
  constexpr size_t OFF_PO    = OFF_HBUF + 65536;             // 8 MB
  constexpr size_t OFF_XB    = OFF_PO + 8388608;             // 64 MB bf16
  constexpr size_t OFF_W4XT  = OFF_XB + 67108864;            // 2 MB
  constexpr size_t OFF_W4HT  = OFF_W4XT + 2097152;           // 2 MB
  constexpr size_t OFF_BIAS  = OFF_W4HT + 2097152;           // 8 KB
  constexpr size_t OFF_G0    = OFF_BIAS + 8192;
  constexpr size_t TOT_F32   = OFF_G0 + (size_t)65536 * 2048 * 4;
  bool g32 = (ws_size >= TOT_F32);

  u32* flags     = (u32*)(ws + OFF_FLAGS);
  u16* h_buf     = (u16*)(ws + OFF_HBUF);
  float* po      = (float*)(ws + OFF_PO);
  u16* xb        = (u16*)(ws + OFF_XB);
  u16* w4xt      = (u16*)(ws + OFF_W4XT);
  u16* w4ht      = (u16*)(ws + OFF_W4HT);
  float* bias4   = (float*)(ws + OFF_BIAS);
  char* gates0   = ws + OFF_G0;

  // zero flags + h_buf every launch (determinism across graph replays)
  hipMemsetAsync(d_ws, 0, OFF_PO, stream);

  k_cast_x<<<16384, 256, 0, stream>>>(x, xb);
  k_pack_w<<<1025, 256, 0, stream>>>(Wxi, Whi, bi, Wxf, Whf, bfv, Wxo, Who, bo,
                                     Wxc, Whc, bc, w4xt, w4ht, bias4);
  if (g32) {
    k_gemm<1><<<8192, 256, 0, stream>>>(xb, w4xt, bias4, gates0);
    k_rnn<1><<<NWG, 256, 0, stream>>>(w4ht, gates0, Wd, h_buf, po, flags);
  } else {
    k_gemm<0><<<8192, 256, 0, stream>>>(xb, w4xt, bias4, gates0);
    k_rnn<0><<<NWG, 256, 0, stream>>>(w4ht, gates0, Wd, h_buf, po, flags);
  }
  k_reduce<<<256, 256, 0, stream>>>(po, bd, (float*)d_out);
}